// Round 7
// baseline (958.526 us; speedup 1.0000x reference)
//
#include <hip/hip_runtime.h>
#include <hip/hip_fp16.h>
#include <hip/hip_cooperative_groups.h>

namespace cg = cooperative_groups;

// TV Chambolle, image (8, 2048, 128) f32: 29 p-updates + final out = x + div(p) + bias.
// v = b*SB + t*ST + f.
//
// R19 = R13 cone geometry (RR=8, EE=16, HH=4, 2 x GR=8, fp32 P in regs, DPP
// b-shifts, fp16 inter-phase p) as ONE persistent cooperative kernel:
//  - 8 dispatches -> 1. Phase boundary = write owned p (fp16, ping-pong
//    pA/pB) + __threadfence + grid.sync + reload the 8 HALO rows only.
//  - Xr (x) loaded ONCE, lives in registers all 29 iterations (~100 MB saved).
//  - Owned p never leaves registers (reads saved, and no fp16 rounding of
//    owned state -> numerics >= R13).
//  - k_final folded into the kernel tail: one p1-row neighbor exchange +
//    publish(p2b/p1if) + phase_out + bias.
//  - Occupancy route (R14-R18) abandoned: toolchain pins VGPR caps at 64 for
//    any 4-waves/EU request; (512,2) is the only sane bound. Latency attack
//    here is structural: no cold restarts, halved p reads.
// Ping-pong safety: reader's halo read of buf happens before its next
// grid.sync; writer re-writes that buf only after passing that sync.

#define BB 8
#define TT 2048
#define FF 128
#define NV (BB*TT*FF)        // 2,097,152
#define SB (TT*FF)           // 262144
#define ST FF                // 128
#define RR 8                 // owned t-rows per block
#define NBLK (TT/RR)         // 256
#define HH 4                 // cone iterations per phase
#define EE 16                // extended rows
#define GR 8                 // rows per row-group

constexpr float TAU = 1.0f / 6.0f;

__device__ __forceinline__ float4 ld4(const float* p) { return *reinterpret_cast<const float4*>(p); }
__device__ __forceinline__ void st4(float* p, const float4& v) { *reinterpret_cast<float4*>(p) = v; }
// packed fp16 <-> fp32x4 (8-byte transactions)
__device__ __forceinline__ float4 ld4h(const __half* p) {
    uint2 u = *reinterpret_cast<const uint2*>(p);
    __half2 h0 = *reinterpret_cast<__half2*>(&u.x);
    __half2 h1 = *reinterpret_cast<__half2*>(&u.y);
    float2 a = __half22float2(h0), b2 = __half22float2(h1);
    return make_float4(a.x, a.y, b2.x, b2.y);
}
__device__ __forceinline__ void st4h(__half* p, const float4& v) {
    __half2 h0 = __float22half2_rn(make_float2(v.x, v.y));
    __half2 h1 = __float22half2_rn(make_float2(v.z, v.w));
    uint2 u;
    u.x = *reinterpret_cast<unsigned*>(&h0);
    u.y = *reinterpret_cast<unsigned*>(&h1);
    *reinterpret_cast<uint2*>(p) = u;
}
// DPP lane shifts (VALU, no DS pipe). row_shr:1 = src[n-1] (shfl_up 1);
// row_shl:1 = src[n+1] (shfl_down 1). 16-lane-row boundary lanes -> 0
// (bound_ctrl=1); all consumers masked by b>0 / b<BB-1 which covers them.
__device__ __forceinline__ float dpp_shr1(float v) {
    return __int_as_float(__builtin_amdgcn_update_dpp(
        0, __float_as_int(v), 0x111, 0xF, 0xF, true));
}
__device__ __forceinline__ float dpp_shl1(float v) {
    return __int_as_float(__builtin_amdgcn_update_dpp(
        0, __float_as_int(v), 0x101, 0xF, 0xF, true));
}
__device__ __forceinline__ float4 dpp_up4(const float4& v) {
    return make_float4(dpp_shr1(v.x), dpp_shr1(v.y), dpp_shr1(v.z), dpp_shr1(v.w));
}
__device__ __forceinline__ float4 dpp_dn4(const float4& v) {
    return make_float4(dpp_shl1(v.x), dpp_shl1(v.y), dpp_shl1(v.z), dpp_shl1(v.w));
}
__device__ __forceinline__ float4 sub4(const float4& a, const float4& b) {
    return make_float4(a.x - b.x, a.y - b.y, a.z - b.z, a.w - b.w);
}
__device__ __forceinline__ float4 f4z() { return make_float4(0.f, 0.f, 0.f, 0.f); }
// 1/(|g|*s + 1) elementwise; v_sqrt_f32 + v_rcp_f32 approx.
__device__ __forceinline__ float4 nbvec(const float4& gB, const float4& gT, const float4& gF, float s) {
    float4 nb; float q;
    q = gB.x * gB.x + gT.x * gT.x + gF.x * gF.x;
    nb.x = __builtin_amdgcn_rcpf(fmaf(__builtin_amdgcn_sqrtf(q), s, 1.f));
    q = gB.y * gB.y + gT.y * gT.y + gF.y * gF.y;
    nb.y = __builtin_amdgcn_rcpf(fmaf(__builtin_amdgcn_sqrtf(q), s, 1.f));
    q = gB.z * gB.z + gT.z * gT.z + gF.z * gF.z;
    nb.z = __builtin_amdgcn_rcpf(fmaf(__builtin_amdgcn_sqrtf(q), s, 1.f));
    q = gB.w * gB.w + gT.w * gT.w + gF.w * gF.w;
    nb.w = __builtin_amdgcn_rcpf(fmaf(__builtin_amdgcn_sqrtf(q), s, 1.f));
    return nb;
}

struct ConeShared {                      // ~10 KB
    float p2b[EE][4][8];                 // p2.w at fg==7 per [row][w][b]
    float outx[EE][4][8];                // out.x at fg==0 per [row][w][b]
    float4 p1if[256];                    // group0's P1[row GR-1] per column
    float4 oif[256];                     // group1's O[row GR]   per column
};

// ---- cone phases (no barriers inside) ----
template<int RG>
__device__ __forceinline__ void publish(int k, float4 (&P1)[GR], float4 (&P2)[GR],
                                        ConeShared& sh, int c, int b, int fg, int w) {
    if (fg == 7) {
        #pragma unroll
        for (int le = 0; le < GR; ++le) {
            const int e = RG * GR + le;
            if (e >= k && e < EE - k) sh.p2b[e][w][b] = P2[le].w;
        }
    }
    if (RG == 0) sh.p1if[c] = P1[GR - 1];
}

template<int RG, bool ELO, bool EHI>
__device__ __forceinline__ void phase_out(
    int k, const float4 (&Xr)[GR],
    float4 (&P0)[GR], float4 (&P1)[GR], float4 (&P2)[GR], float4 (&O)[GR],
    ConeShared& sh, int c, int b, int fg, int w, int f0, int tb) {
    #pragma unroll
    for (int le = 0; le < GR; ++le) {
        const int e = RG * GR + le;
        if (e < k + 1 || e >= EE - k) continue;          // compile-time row kill
        const int t = tb + e;
        if ((ELO && t < 0) || (EHI && t >= TT)) continue;
        const float4 X = Xr[le];
        float4 o;
        o.x = X.x - P0[le].x - P1[le].x - P2[le].x;
        o.y = X.y - P0[le].y - P1[le].y - P2[le].y + P2[le].x;
        o.z = X.z - P0[le].z - P1[le].z - P2[le].z + P2[le].y;
        o.w = X.w - P0[le].w - P1[le].w - P2[le].w + P2[le].z;
        float4 h0 = dpp_up4(P0[le]);                     // p0 at b-1 (DPP, no DS)
        if (b > 0) { o.x += h0.x; o.y += h0.y; o.z += h0.z; o.w += h0.w; }
        float4 pm1 = (le > 0) ? P1[le - 1] : sh.p1if[c]; // p1 at t-1 (LDS only RG1,le0)
        if (!ELO || t > 0) { o.x += pm1.x; o.y += pm1.y; o.z += pm1.z; o.w += pm1.w; }
        float pw = __shfl_up(P2[le].w, 8);               // p2.w at f0-4
        if (fg == 0) pw = (w > 0) ? sh.p2b[e][(w - 1)][b] : 0.0f;
        if (f0 > 0) o.x += pw;
        O[le] = o;
        if (fg == 0) sh.outx[e][w][b] = o.x;
    }
}

template<int RG, bool ELO, bool EHI>
__device__ __forceinline__ void phase_upd(
    int k, float4 (&P0)[GR], float4 (&P1)[GR], float4 (&P2)[GR], float4 (&O)[GR],
    ConeShared& sh, int c, int b, int fg, int w, int f0, int tb, float s) {
    #pragma unroll
    for (int le = 0; le < GR; ++le) {
        const int e = RG * GR + le;
        if (e < k + 1 || e > EE - 2 - k) continue;       // compile-time row kill
        const int t = tb + e;
        if ((ELO && t < 0) || (EHI && t >= TT)) continue;
        const float4 cc = O[le];
        const float4 on = (le < GR - 1) ? O[le + 1] : sh.oif[c];  // oif only RG0,le=GR-1
        float4 gT = f4z();
        if (!EHI || t < TT - 1) gT = sub4(on, cc);
        const float4 nB = dpp_dn4(cc);                   // out at b+1 (DPP, no DS)
        float4 gB = f4z();
        if (b < BB - 1) gB = sub4(nB, cc);
        float nxx = __shfl_down(cc.x, 8);                // out.x at f0+4
        if (fg == 7) nxx = (w < 3) ? sh.outx[e][w + 1][b] : 0.0f;
        float4 gF;
        gF.x = cc.y - cc.x;
        gF.y = cc.z - cc.y;
        gF.z = cc.w - cc.z;
        gF.w = (f0 < FF - 4) ? (nxx - cc.w) : 0.f;
        const float4 nb = nbvec(gB, gT, gF, s);
        P0[le].x = fmaf(-TAU, gB.x, P0[le].x) * nb.x;
        P0[le].y = fmaf(-TAU, gB.y, P0[le].y) * nb.y;
        P0[le].z = fmaf(-TAU, gB.z, P0[le].z) * nb.z;
        P0[le].w = fmaf(-TAU, gB.w, P0[le].w) * nb.w;
        P1[le].x = fmaf(-TAU, gT.x, P1[le].x) * nb.x;
        P1[le].y = fmaf(-TAU, gT.y, P1[le].y) * nb.y;
        P1[le].z = fmaf(-TAU, gT.z, P1[le].z) * nb.z;
        P1[le].w = fmaf(-TAU, gT.w, P1[le].w) * nb.w;
        P2[le].x = fmaf(-TAU, gF.x, P2[le].x) * nb.x;
        P2[le].y = fmaf(-TAU, gF.y, P2[le].y) * nb.y;
        P2[le].z = fmaf(-TAU, gF.z, P2[le].z) * nb.z;
        P2[le].w = fmaf(-TAU, gF.w, P2[le].w) * nb.w;
    }
}

// barriers live here, block-uniform; rg branches wrap only barrier-free compute
template<bool ELO, bool EHI>
__device__ __forceinline__ void cone_run(
    const float4 (&Xr)[GR],
    float4 (&P0)[GR], float4 (&P1)[GR], float4 (&P2)[GR], float4 (&O)[GR],
    ConeShared& sh, int rg, int c, int b, int fg, int w, int f0, int tb, float s) {
    #pragma unroll
    for (int k = 0; k < HH; ++k) {
        if (rg == 0) publish<0>(k, P1, P2, sh, c, b, fg, w);
        else         publish<1>(k, P1, P2, sh, c, b, fg, w);
        __syncthreads();
        if (rg == 0) phase_out<0, ELO, EHI>(k, Xr, P0, P1, P2, O, sh, c, b, fg, w, f0, tb);
        else         phase_out<1, ELO, EHI>(k, Xr, P0, P1, P2, O, sh, c, b, fg, w, f0, tb);
        if (rg == 1) sh.oif[c] = O[0];                   // out at row GR
        __syncthreads();
        if (rg == 0) phase_upd<0, ELO, EHI>(k, P0, P1, P2, O, sh, c, b, fg, w, f0, tb, s);
        else         phase_upd<1, ELO, EHI>(k, P0, P1, P2, O, sh, c, b, fg, w, f0, tb, s);
    }
}

// ==================== persistent main ====================
template<bool ELO, bool EHI>
__device__ __forceinline__ void persist_main(
    const float* __restrict__ x, __half* __restrict__ pA, __half* __restrict__ pB,
    const float* __restrict__ bias, float* __restrict__ out,
    ConeShared& sh, int rg, int c, int b, int fg, int w, int f0, int tb, int e0,
    int base, float s) {
    float4 P0[GR], P1[GR], P2[GR], O[GR], Xr[GR], XHa;
    // ---- X loaded once; persists in registers for all 29 iterations ----
    #pragma unroll
    for (int le = 0; le < GR; ++le) {
        const int t = tb + e0 + le;
        const bool ok = (!ELO || t >= 0) && (!EHI || t < TT);
        Xr[le] = ok ? ld4(x + base + t * ST) : f4z();
        O[le] = f4z();
    }
    {
        const int t = tb + e0 + GR;
        const bool ok = (!ELO || t >= 0) && (t < TT);
        XHa = ok ? ld4(x + base + t * ST) : f4z();
    }
    // ---- iteration 1: p = -TAU*grad(x) / (|grad(x)|*s + 1) ----
    #pragma unroll
    for (int le = 0; le < GR; ++le) {
        const int t = tb + e0 + le;
        if ((!ELO || t >= 0) && (!EHI || t < TT)) {
            const float4 cc = Xr[le];
            const float4 nxt = (le < GR - 1) ? Xr[le + 1] : XHa;
            float4 gT = f4z();
            if (t < TT - 1) gT = sub4(nxt, cc);
            const float4 nB = dpp_dn4(cc);
            float4 gB = f4z();
            if (b < BB - 1) gB = sub4(nB, cc);
            float4 gF;
            gF.x = cc.y - cc.x;
            gF.y = cc.z - cc.y;
            gF.z = cc.w - cc.z;
            gF.w = (f0 < FF - 4) ? (x[base + t * ST + 4] - cc.w) : 0.f;
            const float4 nb = nbvec(gB, gT, gF, s);
            P0[le] = make_float4(-TAU * gB.x * nb.x, -TAU * gB.y * nb.y,
                                 -TAU * gB.z * nb.z, -TAU * gB.w * nb.w);
            P1[le] = make_float4(-TAU * gT.x * nb.x, -TAU * gT.y * nb.y,
                                 -TAU * gT.z * nb.z, -TAU * gT.w * nb.w);
            P2[le] = make_float4(-TAU * gF.x * nb.x, -TAU * gF.y * nb.y,
                                 -TAU * gF.z * nb.z, -TAU * gF.w * nb.w);
        } else {
            P0[le] = f4z(); P1[le] = f4z(); P2[le] = f4z();
        }
    }
    // ---- cone iters 2..5 ----
    cone_run<ELO, EHI>(Xr, P0, P1, P2, O, sh, rg, c, b, fg, w, f0, tb, s);
    // ---- 6 phases x 4 iterations (iters 6..29) ----
    for (int ph = 0; ph < 6; ++ph) {
        __half* buf = (ph & 1) ? pB : pA;
        // write owned rows (fp16) for neighbors
        #pragma unroll
        for (int le = 0; le < GR; ++le) {
            const int e = e0 + le;
            if (e >= HH && e < HH + RR) {                // owned: t always valid
                const int v = base + (tb + e) * ST;
                st4h(buf + v, P0[le]);
                st4h(buf + NV + v, P1[le]);
                st4h(buf + 2 * NV + v, P2[le]);
            }
        }
        __threadfence();
        cg::this_grid().sync();
        // reload HALO rows only (owned p + all of X stay in registers)
        #pragma unroll
        for (int le = 0; le < GR; ++le) {
            const bool halo = (rg == 0) ? (le < HH) : (le >= GR - HH);
            if (halo) {
                const int t = tb + e0 + le;
                const bool ok = (!ELO || t >= 0) && (!EHI || t < TT);
                const bool trim = (rg == 0 && le == 0);  // row 0: only P1 ever read
                if (ok) {
                    const int v = base + t * ST;
                    P1[le] = ld4h(buf + NV + v);
                    if (!trim) {
                        P0[le] = ld4h(buf + v);
                        P2[le] = ld4h(buf + 2 * NV + v);
                    } else { P0[le] = f4z(); P2[le] = f4z(); }
                } else {
                    P0[le] = f4z(); P1[le] = f4z(); P2[le] = f4z();
                }
            }
        }
        cone_run<ELO, EHI>(Xr, P0, P1, P2, O, sh, rg, c, b, fg, w, f0, tb, s);
    }
    // ---- final: out = x + div(p) + bias (k_final folded in) ----
    // neighbor above needs p1 at my last owned row (its halo row HH-1)
    if (rg == 1) {
        const int t = tb + HH + RR - 1;                  // e = 11, le = 3
        st4h(pA + NV + base + t * ST, P1[HH + RR - 1 - GR]);
    }
    // publish p2b (owned rows [HH, HH+RR)) + p1if for the final div
    if (rg == 0) publish<0>(HH, P1, P2, sh, c, b, fg, w);
    else         publish<1>(HH, P1, P2, sh, c, b, fg, w);
    __threadfence();
    cg::this_grid().sync();
    if (rg == 0) {                                       // p1 at t-1 of first owned row
        const int t = tb + HH - 1;
        if (!ELO || t >= 0) P1[HH - 1] = ld4h(pA + NV + base + t * ST);
    }
    // div via phase_out at k=HH-1 (covers owned rows; extra row unused)
    if (rg == 0) phase_out<0, ELO, EHI>(HH - 1, Xr, P0, P1, P2, O, sh, c, b, fg, w, f0, tb);
    else         phase_out<1, ELO, EHI>(HH - 1, Xr, P0, P1, P2, O, sh, c, b, fg, w, f0, tb);
    const float4 bi = ld4(bias + f0);
    #pragma unroll
    for (int le = 0; le < GR; ++le) {
        const int e = e0 + le;
        if (e >= HH && e < HH + RR) {
            const int t = tb + e;
            const float4 o = O[le];
            st4(out + base + t * ST,
                make_float4(o.x + bi.x, o.y + bi.y, o.z + bi.z, o.w + bi.w));
        }
    }
}

__global__ __launch_bounds__(512, 2)
void k_persist(const float* __restrict__ x, __half* __restrict__ pA,
               __half* __restrict__ pB, const float* __restrict__ lam,
               const float* __restrict__ bias, float* __restrict__ out) {
    __shared__ ConeShared sh;
    const int tid = threadIdx.x;
    const int blk = blockIdx.x;
    const int rg  = tid >> 8;
    const int c   = tid & 255;
    const int b   = tid & 7;
    const int fg  = (tid >> 3) & 7;
    const int w   = (tid >> 6) & 3;
    const int f0  = w * 32 + fg * 4;
    const int tb  = blk * RR - HH;
    const int e0  = rg * GR;
    const int base = b * SB + f0;
    const float s = TAU / lam[0];
    if (blk == 0 || blk == NBLK - 1)
        persist_main<true, true>(x, pA, pB, bias, out, sh, rg, c, b, fg, w, f0, tb, e0, base, s);
    else
        persist_main<false, false>(x, pA, pB, bias, out, sh, rg, c, b, fg, w, f0, tb, e0, base, s);
}

extern "C" void kernel_launch(void* const* d_in, const int* in_sizes, int n_in,
                              void* d_out, int out_size, void* d_ws, size_t ws_size,
                              hipStream_t stream) {
    const float* x    = (const float*)d_in[0];
    const float* lam  = (const float*)d_in[1];
    const float* bias = (const float*)d_in[2];
    float* out = (float*)d_out;

    __half* pA = (__half*)d_ws;                   // 3*NV halfs = 12.6 MB
    __half* pB = pA + 3 * NV;

    void* args[] = {(void*)&x, (void*)&pA, (void*)&pB,
                    (void*)&lam, (void*)&bias, (void*)&out};
    hipLaunchCooperativeKernel((void*)k_persist, dim3(NBLK), dim3(512),
                               args, 0, stream);
}

// Round 8
// 256.099 us; speedup vs baseline: 3.7428x; 3.7428x over previous
//
#include <hip/hip_runtime.h>
#include <hip/hip_fp16.h>

// TV Chambolle, image (8, 2048, 128) f32: 29 p-updates + final out = x + div(p) + bias.
// v = b*SB + t*ST + f.
//
// R20 = R13 geometry EXACTLY (RR=8, EE=16, HH=4, NG=2 x GR=8, 512-thr blocks,
// 8 dispatches, 2 barriers/iter, DPP b-shifts, fp16 p between launches) with
// register state PACKED to fit the 128-VGPR occupancy step:
//  - P0/P1/P2 as h4 (half2 pairs): 48 VGPRs. Xr/XHa packed h4: 18. O fp32: 32.
//    Total ~98 + temps ~= 120 < 128.
//  - Why: R19 proved the allocator pins at 128 and spills anything bigger
//    (k_persist: VGPR=128, +40MB spill writes, spill-latency 3.7x). A state
//    that truly fits 128 is the only spill-free design; it also makes the
//    hardware resident 2 blocks/CU = 4 waves/SIMD from the actual count.
//  - Numerics: packed-P per-iteration rounding validated R16/R18 (absmax
//    0.015625 unchanged). Packed Xr only affects iteration dynamics; k_final
//    reads f32 x for the actual output. Est absmax <= 0.02, threshold 0.0956.
//  - Diagnostic round: if VGPR<=128 + no spill + time ~unchanged, the
//    occupancy theory is disproven and we pivot to barrier/launch structure.

#define BB 8
#define TT 2048
#define FF 128
#define NV (BB*TT*FF)        // 2,097,152
#define SB (TT*FF)           // 262144
#define ST FF                // 128
#define RR 8                 // owned t-rows per block
#define NBLK (TT/RR)         // 256
#define HH 4                 // cone iterations per launch
#define EE 16                // extended rows
#define GR 8                 // rows per row-group (2 groups)

constexpr float TAU = 1.0f / 6.0f;

__device__ __forceinline__ float4 ld4(const float* p) { return *reinterpret_cast<const float4*>(p); }
__device__ __forceinline__ void st4(float* p, const float4& v) { *reinterpret_cast<float4*>(p) = v; }

// packed 4 x fp16 (2 VGPRs)
struct h4 { __half2 lo, hi; };
__device__ __forceinline__ float4 h2f(const h4& h) {
    float2 a = __half22float2(h.lo), b = __half22float2(h.hi);
    return make_float4(a.x, a.y, b.x, b.y);
}
__device__ __forceinline__ h4 f2h(const float4& v) {
    h4 r;
    r.lo = __float22half2_rn(make_float2(v.x, v.y));
    r.hi = __float22half2_rn(make_float2(v.z, v.w));
    return r;
}
__device__ __forceinline__ h4 h4z() {
    h4 r; unsigned z = 0;
    r.lo = *reinterpret_cast<__half2*>(&z);
    r.hi = *reinterpret_cast<__half2*>(&z);
    return r;
}
__device__ __forceinline__ h4 ld4hp(const __half* p) {   // raw 8B, no cvt
    uint2 u = *reinterpret_cast<const uint2*>(p);
    h4 r;
    r.lo = *reinterpret_cast<__half2*>(&u.x);
    r.hi = *reinterpret_cast<__half2*>(&u.y);
    return r;
}
__device__ __forceinline__ void st4hp(__half* p, const h4& v) {  // raw 8B, no cvt
    uint2 u;
    u.x = *reinterpret_cast<const unsigned*>(&v.lo);
    u.y = *reinterpret_cast<const unsigned*>(&v.hi);
    *reinterpret_cast<uint2*>(p) = u;
}
__device__ __forceinline__ float4 ld4h(const __half* p) { return h2f(ld4hp(p)); }

// DPP lane shifts (VALU, no DS pipe). row_shr:1 = src[n-1] (shfl_up 1);
// row_shl:1 = src[n+1] (shfl_down 1). 16-lane-row boundary lanes -> 0
// (bound_ctrl=1); all consumers masked by b>0 / b<BB-1 which covers them.
__device__ __forceinline__ float dpp_shl1(float v) {
    return __int_as_float(__builtin_amdgcn_update_dpp(
        0, __float_as_int(v), 0x101, 0xF, 0xF, true));
}
__device__ __forceinline__ float4 dpp_dn4(const float4& v) {
    return make_float4(dpp_shl1(v.x), dpp_shl1(v.y), dpp_shl1(v.z), dpp_shl1(v.w));
}
__device__ __forceinline__ h4 dpp_up_h4(const h4& v) {   // packed: 2 DPP ops
    unsigned lo = *reinterpret_cast<const unsigned*>(&v.lo);
    unsigned hi = *reinterpret_cast<const unsigned*>(&v.hi);
    unsigned rl = (unsigned)__builtin_amdgcn_update_dpp(0, (int)lo, 0x111, 0xF, 0xF, true);
    unsigned rh = (unsigned)__builtin_amdgcn_update_dpp(0, (int)hi, 0x111, 0xF, 0xF, true);
    h4 r;
    r.lo = *reinterpret_cast<__half2*>(&rl);
    r.hi = *reinterpret_cast<__half2*>(&rh);
    return r;
}
__device__ __forceinline__ float4 sub4(const float4& a, const float4& b) {
    return make_float4(a.x - b.x, a.y - b.y, a.z - b.z, a.w - b.w);
}
__device__ __forceinline__ float4 f4z() { return make_float4(0.f, 0.f, 0.f, 0.f); }
// 1/(|g|*s + 1) elementwise; v_sqrt_f32 + v_rcp_f32 approx.
__device__ __forceinline__ float4 nbvec(const float4& gB, const float4& gT, const float4& gF, float s) {
    float4 nb; float q;
    q = gB.x * gB.x + gT.x * gT.x + gF.x * gF.x;
    nb.x = __builtin_amdgcn_rcpf(fmaf(__builtin_amdgcn_sqrtf(q), s, 1.f));
    q = gB.y * gB.y + gT.y * gT.y + gF.y * gF.y;
    nb.y = __builtin_amdgcn_rcpf(fmaf(__builtin_amdgcn_sqrtf(q), s, 1.f));
    q = gB.z * gB.z + gT.z * gT.z + gF.z * gF.z;
    nb.z = __builtin_amdgcn_rcpf(fmaf(__builtin_amdgcn_sqrtf(q), s, 1.f));
    q = gB.w * gB.w + gT.w * gT.w + gF.w * gF.w;
    nb.w = __builtin_amdgcn_rcpf(fmaf(__builtin_amdgcn_sqrtf(q), s, 1.f));
    return nb;
}

struct ConeShared {                      // ~8 KB
    float p2b[EE][4][8];                 // p2.w at fg==7 per [row][w][b]
    float outx[EE][4][8];                // out.x at fg==0 per [row][w][b]
    h4 p1if[256];                        // group0's P1[row GR-1] per column (packed)
    float4 oif[256];                     // group1's O[row GR]   per column
};

// ---- cone phases (no barriers inside) ----
template<int RG>
__device__ __forceinline__ void publish(int k, h4 (&P1)[GR], h4 (&P2)[GR],
                                        ConeShared& sh, int c, int b, int fg, int w) {
    if (fg == 7) {
        #pragma unroll
        for (int le = 0; le < GR; ++le) {
            const int e = RG * GR + le;
            if (e >= k && e < EE - k) sh.p2b[e][w][b] = __high2float(P2[le].hi);
        }
    }
    if (RG == 0) sh.p1if[c] = P1[GR - 1];
}

template<int RG, bool ELO, bool EHI>
__device__ __forceinline__ void phase_out(
    int k, const h4 (&Xr)[GR],
    h4 (&P0)[GR], h4 (&P1)[GR], h4 (&P2)[GR], float4 (&O)[GR],
    ConeShared& sh, int c, int b, int fg, int w, int f0, int tb) {
    #pragma unroll
    for (int le = 0; le < GR; ++le) {
        const int e = RG * GR + le;
        if (e < k + 1 || e >= EE - k) continue;          // compile-time row kill
        const int t = tb + e;
        if ((ELO && t < 0) || (EHI && t >= TT)) continue;
        const float4 X = h2f(Xr[le]);
        const float4 p0 = h2f(P0[le]);
        const float4 p1 = h2f(P1[le]);
        const float4 p2 = h2f(P2[le]);
        float4 o;
        o.x = X.x - p0.x - p1.x - p2.x;
        o.y = X.y - p0.y - p1.y - p2.y + p2.x;
        o.z = X.z - p0.z - p1.z - p2.z + p2.y;
        o.w = X.w - p0.w - p1.w - p2.w + p2.z;
        const float4 h0 = h2f(dpp_up_h4(P0[le]));        // p0 at b-1 (packed DPP)
        if (b > 0) { o.x += h0.x; o.y += h0.y; o.z += h0.z; o.w += h0.w; }
        const h4 pm1h = (le > 0) ? P1[le - 1] : sh.p1if[c];  // p1 at t-1
        const float4 pm1 = h2f(pm1h);
        if (!ELO || t > 0) { o.x += pm1.x; o.y += pm1.y; o.z += pm1.z; o.w += pm1.w; }
        float pw = __shfl_up(p2.w, 8);                   // p2.w at f0-4
        if (fg == 0) pw = (w > 0) ? sh.p2b[e][(w - 1)][b] : 0.0f;
        if (f0 > 0) o.x += pw;
        O[le] = o;
        if (fg == 0) sh.outx[e][w][b] = o.x;
    }
}

template<int RG, bool ELO, bool EHI>
__device__ __forceinline__ void phase_upd(
    int k, h4 (&P0)[GR], h4 (&P1)[GR], h4 (&P2)[GR], float4 (&O)[GR],
    ConeShared& sh, int c, int b, int fg, int w, int f0, int tb, float s) {
    #pragma unroll
    for (int le = 0; le < GR; ++le) {
        const int e = RG * GR + le;
        if (e < k + 1 || e > EE - 2 - k) continue;       // compile-time row kill
        const int t = tb + e;
        if ((ELO && t < 0) || (EHI && t >= TT)) continue;
        const float4 cc = O[le];
        const float4 on = (le < GR - 1) ? O[le + 1] : sh.oif[c];  // oif only RG0,le=GR-1
        float4 gT = f4z();
        if (!EHI || t < TT - 1) gT = sub4(on, cc);
        const float4 nB = dpp_dn4(cc);                   // out at b+1 (DPP)
        float4 gB = f4z();
        if (b < BB - 1) gB = sub4(nB, cc);
        float nxx = __shfl_down(cc.x, 8);                // out.x at f0+4
        if (fg == 7) nxx = (w < 3) ? sh.outx[e][w + 1][b] : 0.0f;
        float4 gF;
        gF.x = cc.y - cc.x;
        gF.y = cc.z - cc.y;
        gF.z = cc.w - cc.z;
        gF.w = (f0 < FF - 4) ? (nxx - cc.w) : 0.f;
        const float4 nb = nbvec(gB, gT, gF, s);
        const float4 p0 = h2f(P0[le]);
        const float4 p1 = h2f(P1[le]);
        const float4 p2 = h2f(P2[le]);
        float4 n0, n1, n2;
        n0.x = fmaf(-TAU, gB.x, p0.x) * nb.x;
        n0.y = fmaf(-TAU, gB.y, p0.y) * nb.y;
        n0.z = fmaf(-TAU, gB.z, p0.z) * nb.z;
        n0.w = fmaf(-TAU, gB.w, p0.w) * nb.w;
        n1.x = fmaf(-TAU, gT.x, p1.x) * nb.x;
        n1.y = fmaf(-TAU, gT.y, p1.y) * nb.y;
        n1.z = fmaf(-TAU, gT.z, p1.z) * nb.z;
        n1.w = fmaf(-TAU, gT.w, p1.w) * nb.w;
        n2.x = fmaf(-TAU, gF.x, p2.x) * nb.x;
        n2.y = fmaf(-TAU, gF.y, p2.y) * nb.y;
        n2.z = fmaf(-TAU, gF.z, p2.z) * nb.z;
        n2.w = fmaf(-TAU, gF.w, p2.w) * nb.w;
        P0[le] = f2h(n0);
        P1[le] = f2h(n1);
        P2[le] = f2h(n2);
    }
}

// barriers live here, block-uniform; rg branches wrap only barrier-free compute
template<bool ELO, bool EHI>
__device__ __forceinline__ void cone_run(
    const h4 (&Xr)[GR],
    h4 (&P0)[GR], h4 (&P1)[GR], h4 (&P2)[GR], float4 (&O)[GR],
    ConeShared& sh, int rg, int c, int b, int fg, int w, int f0, int tb, float s) {
    #pragma unroll
    for (int k = 0; k < HH; ++k) {
        if (rg == 0) publish<0>(k, P1, P2, sh, c, b, fg, w);
        else         publish<1>(k, P1, P2, sh, c, b, fg, w);
        __syncthreads();
        if (rg == 0) phase_out<0, ELO, EHI>(k, Xr, P0, P1, P2, O, sh, c, b, fg, w, f0, tb);
        else         phase_out<1, ELO, EHI>(k, Xr, P0, P1, P2, O, sh, c, b, fg, w, f0, tb);
        if (rg == 1) sh.oif[c] = O[0];                   // out at row GR
        __syncthreads();
        if (rg == 0) phase_upd<0, ELO, EHI>(k, P0, P1, P2, O, sh, c, b, fg, w, f0, tb, s);
        else         phase_upd<1, ELO, EHI>(k, P0, P1, P2, O, sh, c, b, fg, w, f0, tb, s);
    }
}

// ==================== mid launch: 4 cone iterations (fp16 p in/out) ====================
template<bool ELO, bool EHI>
__device__ __forceinline__ void mid_main(
    const float* __restrict__ x, const __half* __restrict__ pin, __half* __restrict__ pout,
    ConeShared& sh, int rg, int c, int b, int fg, int w, int f0, int tb, int e0,
    int base, float s) {
    h4 P0[GR], P1[GR], P2[GR], Xr[GR];
    float4 O[GR];
    #pragma unroll
    for (int le = 0; le < GR; ++le) {
        const int t = tb + e0 + le;
        const bool ok = (!ELO || t >= 0) && (!EHI || t < TT);
        const bool trim = (rg == 0 && le == 0);          // row 0: only P1 ever read
        if (ok) {
            const int v = base + t * ST;
            P1[le] = ld4hp(pin + NV + v);
            if (!trim) {
                P0[le] = ld4hp(pin + v);
                P2[le] = ld4hp(pin + 2 * NV + v);
                Xr[le] = f2h(ld4(x + v));
            } else { P0[le] = h4z(); P2[le] = h4z(); Xr[le] = h4z(); }
        } else {
            P0[le] = h4z(); P1[le] = h4z(); P2[le] = h4z(); Xr[le] = h4z();
        }
        O[le] = f4z();
    }
    cone_run<ELO, EHI>(Xr, P0, P1, P2, O, sh, rg, c, b, fg, w, f0, tb, s);
    #pragma unroll
    for (int le = 0; le < GR; ++le) {
        const int e = e0 + le;
        if (e >= HH && e < HH + RR) {                    // owned rows: t always valid
            const int v = base + (tb + e) * ST;
            st4hp(pout + v, P0[le]);
            st4hp(pout + NV + v, P1[le]);
            st4hp(pout + 2 * NV + v, P2[le]);
        }
    }
}

__global__ __launch_bounds__(512, 2)
void k_mid(const float* __restrict__ x, const __half* __restrict__ pin,
           __half* __restrict__ pout, const float* __restrict__ lam) {
    __shared__ ConeShared sh;
    const int tid = threadIdx.x;
    const int blk = blockIdx.x;
    const int rg  = tid >> 8;
    const int c   = tid & 255;
    const int b   = tid & 7;
    const int fg  = (tid >> 3) & 7;
    const int w   = (tid >> 6) & 3;
    const int f0  = w * 32 + fg * 4;
    const int tb  = blk * RR - HH;
    const int e0  = rg * GR;
    const int base = b * SB + f0;
    const float s = TAU / lam[0];
    if (blk == 0 || blk == NBLK - 1)
        mid_main<true, true>(x, pin, pout, sh, rg, c, b, fg, w, f0, tb, e0, base, s);
    else
        mid_main<false, false>(x, pin, pout, sh, rg, c, b, fg, w, f0, tb, e0, base, s);
}

// ============ first launch: iter 1 from p==0 (out==x) + 4 cone iters ============
template<bool ELO, bool EHI>
__device__ __forceinline__ void first_main(
    const float* __restrict__ x, __half* __restrict__ pout,
    ConeShared& sh, int rg, int c, int b, int fg, int w, int f0, int tb, int e0,
    int base, float s) {
    h4 P0[GR], P1[GR], P2[GR], Xr[GR], XHa;
    float4 O[GR];
    #pragma unroll
    for (int le = 0; le < GR; ++le) {
        const int t = tb + e0 + le;
        const bool ok = (!ELO || t >= 0) && (!EHI || t < TT);
        Xr[le] = ok ? f2h(ld4(x + base + t * ST)) : h4z();
        O[le] = f4z();
    }
    {
        const int t = tb + e0 + GR;
        const bool ok = (!ELO || t >= 0) && (t < TT);
        XHa = ok ? f2h(ld4(x + base + t * ST)) : h4z();
    }
    // iteration 1: p = -TAU*grad(x) / (|grad(x)|*s + 1) on all valid rows
    #pragma unroll
    for (int le = 0; le < GR; ++le) {
        const int t = tb + e0 + le;
        if ((!ELO || t >= 0) && (!EHI || t < TT)) {
            const float4 cc = h2f(Xr[le]);
            const float4 nxt = (le < GR - 1) ? h2f(Xr[le + 1]) : h2f(XHa);
            float4 gT = f4z();
            if (t < TT - 1) gT = sub4(nxt, cc);
            const float4 nB = dpp_dn4(cc);
            float4 gB = f4z();
            if (b < BB - 1) gB = sub4(nB, cc);
            float4 gF;
            gF.x = cc.y - cc.x;
            gF.y = cc.z - cc.y;
            gF.z = cc.w - cc.z;
            gF.w = (f0 < FF - 4) ? (x[base + t * ST + 4] - cc.w) : 0.f;
            const float4 nb = nbvec(gB, gT, gF, s);
            P0[le] = f2h(make_float4(-TAU * gB.x * nb.x, -TAU * gB.y * nb.y,
                                     -TAU * gB.z * nb.z, -TAU * gB.w * nb.w));
            P1[le] = f2h(make_float4(-TAU * gT.x * nb.x, -TAU * gT.y * nb.y,
                                     -TAU * gT.z * nb.z, -TAU * gT.w * nb.w));
            P2[le] = f2h(make_float4(-TAU * gF.x * nb.x, -TAU * gF.y * nb.y,
                                     -TAU * gF.z * nb.z, -TAU * gF.w * nb.w));
        } else {
            P0[le] = h4z(); P1[le] = h4z(); P2[le] = h4z();
        }
    }
    cone_run<ELO, EHI>(Xr, P0, P1, P2, O, sh, rg, c, b, fg, w, f0, tb, s);
    #pragma unroll
    for (int le = 0; le < GR; ++le) {
        const int e = e0 + le;
        if (e >= HH && e < HH + RR) {
            const int v = base + (tb + e) * ST;
            st4hp(pout + v, P0[le]);
            st4hp(pout + NV + v, P1[le]);
            st4hp(pout + 2 * NV + v, P2[le]);
        }
    }
}

__global__ __launch_bounds__(512, 2)
void k_first(const float* __restrict__ x, __half* __restrict__ pout,
             const float* __restrict__ lam) {
    __shared__ ConeShared sh;
    const int tid = threadIdx.x;
    const int blk = blockIdx.x;
    const int rg  = tid >> 8;
    const int c   = tid & 255;
    const int b   = tid & 7;
    const int fg  = (tid >> 3) & 7;
    const int w   = (tid >> 6) & 3;
    const int f0  = w * 32 + fg * 4;
    const int tb  = blk * RR - HH;
    const int e0  = rg * GR;
    const int base = b * SB + f0;
    const float s = TAU / lam[0];
    if (blk == 0 || blk == NBLK - 1)
        first_main<true, true>(x, pout, sh, rg, c, b, fg, w, f0, tb, e0, base, s);
    else
        first_main<false, false>(x, pout, sh, rg, c, b, fg, w, f0, tb, e0, base, s);
}

// ---- final: out = x + div(p) + bias (fp16 p, f32 x) ----
__global__ __launch_bounds__(256)
void k_final(const float* __restrict__ x, const __half* __restrict__ pin,
             const float* __restrict__ bias, float* __restrict__ out) {
    const int gid = blockIdx.x * 256 + threadIdx.x;
    const int v = gid * 4;
    const int f0 = v & (FF - 1);
    const int t = (v >> 7) & (TT - 1);
    const int b = v >> 18;
    const __half* p0 = pin;
    const __half* p1 = pin + NV;
    const __half* p2 = pin + 2 * NV;
    float4 X = ld4(x + v);
    float4 a0 = ld4h(p0 + v), a1 = ld4h(p1 + v), a2 = ld4h(p2 + v);
    float ox = X.x - a0.x - a1.x - a2.x;
    float oy = X.y - a0.y - a1.y - a2.y + a2.x;
    float oz = X.z - a0.z - a1.z - a2.z + a2.y;
    float ow = X.w - a0.w - a1.w - a2.w + a2.z;
    if (b > 0) { float4 h = ld4h(p0 + v - SB); ox += h.x; oy += h.y; oz += h.z; ow += h.w; }
    if (t > 0) { float4 h = ld4h(p1 + v - ST); ox += h.x; oy += h.y; oz += h.z; ow += h.w; }
    if (f0 > 0) ox += __half2float(p2[v - 1]);
    float4 bi = ld4(bias + f0);
    st4(out + v, make_float4(ox + bi.x, oy + bi.y, oz + bi.z, ow + bi.w));
}

extern "C" void kernel_launch(void* const* d_in, const int* in_sizes, int n_in,
                              void* d_out, int out_size, void* d_ws, size_t ws_size,
                              hipStream_t stream) {
    const float* x    = (const float*)d_in[0];
    const float* lam  = (const float*)d_in[1];
    const float* bias = (const float*)d_in[2];
    float* out = (float*)d_out;

    __half* pA = (__half*)d_ws;                   // 3*NV halfs = 12.6 MB
    __half* pB = pA + 3 * NV;

    // iterations 1..5 (iter-1 specialization + 4 cone iters)
    k_first<<<NBLK, 512, 0, stream>>>(x, pA, lam);
    // iterations 6..29: 6 launches x 4
    __half* pin = pA;
    __half* pout = pB;
    for (int i = 0; i < 6; ++i) {
        k_mid<<<NBLK, 512, 0, stream>>>(x, pin, pout, lam);
        __half* tmp = pin; pin = pout; pout = tmp;
    }
    k_final<<<NV / 1024, 256, 0, stream>>>(x, pin, bias, out);
}

// Round 9
// 245.421 us; speedup vs baseline: 3.9056x; 1.0435x over previous
//
#include <hip/hip_runtime.h>
#include <hip/hip_fp16.h>

// TV Chambolle, image (8, 2048, 128) f32: 29 p-updates + final out = x + div(p) + bias.
// v = b*SB + t*ST + f.
//
// R21 = R13 cone kernels EXACTLY (fp32 P, RR=8, EE=16, HH=4, 2 x GR=8, 512-thr,
// DPP b-shifts, fp16 p between launches; 245.7us proven) + the final div+bias
// FUSED into the last cone launch (k_tail), eliminating k_final's 25MB re-read:
//  - k_tail: EE=18 (2 x GR=9, halo 5/5), 4 cone iters, then publish(k=4) ->
//    barrier -> phase_out(k=4) == out rows with 29-update p -> +bias -> store.
//    After 4 iters rows rel [4,12] are exact; owned rel [5,13) and its t-1
//    row (rel 4) all inside. No p written by the tail (dead).
//  - R10/R11's fused-tail spill is fixed by packing P as h4 ONLY in the tail:
//    state = P 54 + Xr 36 + O 36 = 126 + temps ~= 155 (fp32 GR=9 was ~205).
//    Packed-P per-iter rounding validated by R20 (absmax unchanged).
//  - Occupancy lever abandoned for good: R14-R20 proved it null (6 configs).
//  - Cost model from R13-R20: total ~= 29*c + nL*O, c~=6us, O~=7us; HH=4 is
//    the optimum; the only free win left was the k_final round-trip.

#define BB 8
#define TT 2048
#define FF 128
#define NV (BB*TT*FF)        // 2,097,152
#define SB (TT*FF)           // 262144
#define ST FF                // 128
#define RR 8                 // owned t-rows per block
#define NBLK (TT/RR)         // 256
#define HH 4                 // cone iterations per launch
#define EE 16                // extended rows (k_first / k_mid)
#define GR 8                 // rows per row-group (k_first / k_mid)
#define EET 18               // extended rows (k_tail)
#define GRT 9                // rows per row-group (k_tail)
#define HLT 5                // tail halo below owned

constexpr float TAU = 1.0f / 6.0f;

__device__ __forceinline__ float4 ld4(const float* p) { return *reinterpret_cast<const float4*>(p); }
__device__ __forceinline__ void st4(float* p, const float4& v) { *reinterpret_cast<float4*>(p) = v; }
// packed fp16 <-> fp32x4 (8-byte transactions)
__device__ __forceinline__ float4 ld4h(const __half* p) {
    uint2 u = *reinterpret_cast<const uint2*>(p);
    __half2 h0 = *reinterpret_cast<__half2*>(&u.x);
    __half2 h1 = *reinterpret_cast<__half2*>(&u.y);
    float2 a = __half22float2(h0), b2 = __half22float2(h1);
    return make_float4(a.x, a.y, b2.x, b2.y);
}
__device__ __forceinline__ void st4h(__half* p, const float4& v) {
    __half2 h0 = __float22half2_rn(make_float2(v.x, v.y));
    __half2 h1 = __float22half2_rn(make_float2(v.z, v.w));
    uint2 u;
    u.x = *reinterpret_cast<unsigned*>(&h0);
    u.y = *reinterpret_cast<unsigned*>(&h1);
    *reinterpret_cast<uint2*>(p) = u;
}
// packed 4 x fp16 in registers (2 VGPRs) -- tail only
struct h4 { __half2 lo, hi; };
__device__ __forceinline__ float4 h2f(const h4& h) {
    float2 a = __half22float2(h.lo), b = __half22float2(h.hi);
    return make_float4(a.x, a.y, b.x, b.y);
}
__device__ __forceinline__ h4 f2h(const float4& v) {
    h4 r;
    r.lo = __float22half2_rn(make_float2(v.x, v.y));
    r.hi = __float22half2_rn(make_float2(v.z, v.w));
    return r;
}
__device__ __forceinline__ h4 h4z() {
    h4 r; unsigned z = 0;
    r.lo = *reinterpret_cast<__half2*>(&z);
    r.hi = *reinterpret_cast<__half2*>(&z);
    return r;
}
__device__ __forceinline__ h4 ld4hp(const __half* p) {   // raw 8B, no cvt
    uint2 u = *reinterpret_cast<const uint2*>(p);
    h4 r;
    r.lo = *reinterpret_cast<__half2*>(&u.x);
    r.hi = *reinterpret_cast<__half2*>(&u.y);
    return r;
}

// DPP lane shifts (VALU, no DS pipe). row_shr:1 = src[n-1] (shfl_up 1);
// row_shl:1 = src[n+1] (shfl_down 1). 16-lane-row boundary lanes -> 0
// (bound_ctrl=1); all consumers masked by b>0 / b<BB-1 which covers them.
__device__ __forceinline__ float dpp_shr1(float v) {
    return __int_as_float(__builtin_amdgcn_update_dpp(
        0, __float_as_int(v), 0x111, 0xF, 0xF, true));
}
__device__ __forceinline__ float dpp_shl1(float v) {
    return __int_as_float(__builtin_amdgcn_update_dpp(
        0, __float_as_int(v), 0x101, 0xF, 0xF, true));
}
__device__ __forceinline__ float4 dpp_up4(const float4& v) {
    return make_float4(dpp_shr1(v.x), dpp_shr1(v.y), dpp_shr1(v.z), dpp_shr1(v.w));
}
__device__ __forceinline__ float4 dpp_dn4(const float4& v) {
    return make_float4(dpp_shl1(v.x), dpp_shl1(v.y), dpp_shl1(v.z), dpp_shl1(v.w));
}
__device__ __forceinline__ h4 dpp_up_h4(const h4& v) {   // packed: 2 DPP ops
    unsigned lo = *reinterpret_cast<const unsigned*>(&v.lo);
    unsigned hi = *reinterpret_cast<const unsigned*>(&v.hi);
    unsigned rl = (unsigned)__builtin_amdgcn_update_dpp(0, (int)lo, 0x111, 0xF, 0xF, true);
    unsigned rh = (unsigned)__builtin_amdgcn_update_dpp(0, (int)hi, 0x111, 0xF, 0xF, true);
    h4 r;
    r.lo = *reinterpret_cast<__half2*>(&rl);
    r.hi = *reinterpret_cast<__half2*>(&rh);
    return r;
}
__device__ __forceinline__ float4 sub4(const float4& a, const float4& b) {
    return make_float4(a.x - b.x, a.y - b.y, a.z - b.z, a.w - b.w);
}
__device__ __forceinline__ float4 f4z() { return make_float4(0.f, 0.f, 0.f, 0.f); }
// 1/(|g|*s + 1) elementwise; v_sqrt_f32 + v_rcp_f32 approx.
__device__ __forceinline__ float4 nbvec(const float4& gB, const float4& gT, const float4& gF, float s) {
    float4 nb; float q;
    q = gB.x * gB.x + gT.x * gT.x + gF.x * gF.x;
    nb.x = __builtin_amdgcn_rcpf(fmaf(__builtin_amdgcn_sqrtf(q), s, 1.f));
    q = gB.y * gB.y + gT.y * gT.y + gF.y * gF.y;
    nb.y = __builtin_amdgcn_rcpf(fmaf(__builtin_amdgcn_sqrtf(q), s, 1.f));
    q = gB.z * gB.z + gT.z * gT.z + gF.z * gF.z;
    nb.z = __builtin_amdgcn_rcpf(fmaf(__builtin_amdgcn_sqrtf(q), s, 1.f));
    q = gB.w * gB.w + gT.w * gT.w + gF.w * gF.w;
    nb.w = __builtin_amdgcn_rcpf(fmaf(__builtin_amdgcn_sqrtf(q), s, 1.f));
    return nb;
}

// ==================================================================
// ============== fp32 cone (k_first / k_mid) -- R13 =================
// ==================================================================
struct ConeShared {                      // ~10 KB
    float p2b[EE][4][8];
    float outx[EE][4][8];
    float4 p1if[256];
    float4 oif[256];
};

template<int RG>
__device__ __forceinline__ void publish(int k, float4 (&P1)[GR], float4 (&P2)[GR],
                                        ConeShared& sh, int c, int b, int fg, int w) {
    if (fg == 7) {
        #pragma unroll
        for (int le = 0; le < GR; ++le) {
            const int e = RG * GR + le;
            if (e >= k && e < EE - k) sh.p2b[e][w][b] = P2[le].w;
        }
    }
    if (RG == 0) sh.p1if[c] = P1[GR - 1];
}

template<int RG, bool ELO, bool EHI>
__device__ __forceinline__ void phase_out(
    int k, const float4 (&Xr)[GR],
    float4 (&P0)[GR], float4 (&P1)[GR], float4 (&P2)[GR], float4 (&O)[GR],
    ConeShared& sh, int c, int b, int fg, int w, int f0, int tb) {
    #pragma unroll
    for (int le = 0; le < GR; ++le) {
        const int e = RG * GR + le;
        if (e < k + 1 || e >= EE - k) continue;
        const int t = tb + e;
        if ((ELO && t < 0) || (EHI && t >= TT)) continue;
        const float4 X = Xr[le];
        float4 o;
        o.x = X.x - P0[le].x - P1[le].x - P2[le].x;
        o.y = X.y - P0[le].y - P1[le].y - P2[le].y + P2[le].x;
        o.z = X.z - P0[le].z - P1[le].z - P2[le].z + P2[le].y;
        o.w = X.w - P0[le].w - P1[le].w - P2[le].w + P2[le].z;
        float4 h0 = dpp_up4(P0[le]);
        if (b > 0) { o.x += h0.x; o.y += h0.y; o.z += h0.z; o.w += h0.w; }
        float4 pm1 = (le > 0) ? P1[le - 1] : sh.p1if[c];
        if (!ELO || t > 0) { o.x += pm1.x; o.y += pm1.y; o.z += pm1.z; o.w += pm1.w; }
        float pw = __shfl_up(P2[le].w, 8);
        if (fg == 0) pw = (w > 0) ? sh.p2b[e][(w - 1)][b] : 0.0f;
        if (f0 > 0) o.x += pw;
        O[le] = o;
        if (fg == 0) sh.outx[e][w][b] = o.x;
    }
}

template<int RG, bool ELO, bool EHI>
__device__ __forceinline__ void phase_upd(
    int k, float4 (&P0)[GR], float4 (&P1)[GR], float4 (&P2)[GR], float4 (&O)[GR],
    ConeShared& sh, int c, int b, int fg, int w, int f0, int tb, float s) {
    #pragma unroll
    for (int le = 0; le < GR; ++le) {
        const int e = RG * GR + le;
        if (e < k + 1 || e > EE - 2 - k) continue;
        const int t = tb + e;
        if ((ELO && t < 0) || (EHI && t >= TT)) continue;
        const float4 cc = O[le];
        const float4 on = (le < GR - 1) ? O[le + 1] : sh.oif[c];
        float4 gT = f4z();
        if (!EHI || t < TT - 1) gT = sub4(on, cc);
        const float4 nB = dpp_dn4(cc);
        float4 gB = f4z();
        if (b < BB - 1) gB = sub4(nB, cc);
        float nxx = __shfl_down(cc.x, 8);
        if (fg == 7) nxx = (w < 3) ? sh.outx[e][w + 1][b] : 0.0f;
        float4 gF;
        gF.x = cc.y - cc.x;
        gF.y = cc.z - cc.y;
        gF.z = cc.w - cc.z;
        gF.w = (f0 < FF - 4) ? (nxx - cc.w) : 0.f;
        const float4 nb = nbvec(gB, gT, gF, s);
        P0[le].x = fmaf(-TAU, gB.x, P0[le].x) * nb.x;
        P0[le].y = fmaf(-TAU, gB.y, P0[le].y) * nb.y;
        P0[le].z = fmaf(-TAU, gB.z, P0[le].z) * nb.z;
        P0[le].w = fmaf(-TAU, gB.w, P0[le].w) * nb.w;
        P1[le].x = fmaf(-TAU, gT.x, P1[le].x) * nb.x;
        P1[le].y = fmaf(-TAU, gT.y, P1[le].y) * nb.y;
        P1[le].z = fmaf(-TAU, gT.z, P1[le].z) * nb.z;
        P1[le].w = fmaf(-TAU, gT.w, P1[le].w) * nb.w;
        P2[le].x = fmaf(-TAU, gF.x, P2[le].x) * nb.x;
        P2[le].y = fmaf(-TAU, gF.y, P2[le].y) * nb.y;
        P2[le].z = fmaf(-TAU, gF.z, P2[le].z) * nb.z;
        P2[le].w = fmaf(-TAU, gF.w, P2[le].w) * nb.w;
    }
}

template<bool ELO, bool EHI>
__device__ __forceinline__ void cone_run(
    const float4 (&Xr)[GR],
    float4 (&P0)[GR], float4 (&P1)[GR], float4 (&P2)[GR], float4 (&O)[GR],
    ConeShared& sh, int rg, int c, int b, int fg, int w, int f0, int tb, float s) {
    #pragma unroll
    for (int k = 0; k < HH; ++k) {
        if (rg == 0) publish<0>(k, P1, P2, sh, c, b, fg, w);
        else         publish<1>(k, P1, P2, sh, c, b, fg, w);
        __syncthreads();
        if (rg == 0) phase_out<0, ELO, EHI>(k, Xr, P0, P1, P2, O, sh, c, b, fg, w, f0, tb);
        else         phase_out<1, ELO, EHI>(k, Xr, P0, P1, P2, O, sh, c, b, fg, w, f0, tb);
        if (rg == 1) sh.oif[c] = O[0];
        __syncthreads();
        if (rg == 0) phase_upd<0, ELO, EHI>(k, P0, P1, P2, O, sh, c, b, fg, w, f0, tb, s);
        else         phase_upd<1, ELO, EHI>(k, P0, P1, P2, O, sh, c, b, fg, w, f0, tb, s);
    }
}

template<bool ELO, bool EHI>
__device__ __forceinline__ void mid_main(
    const float* __restrict__ x, const __half* __restrict__ pin, __half* __restrict__ pout,
    ConeShared& sh, int rg, int c, int b, int fg, int w, int f0, int tb, int e0,
    int base, float s) {
    float4 P0[GR], P1[GR], P2[GR], O[GR], Xr[GR];
    #pragma unroll
    for (int le = 0; le < GR; ++le) {
        const int t = tb + e0 + le;
        const bool ok = (!ELO || t >= 0) && (!EHI || t < TT);
        const bool trim = (rg == 0 && le == 0);
        if (ok) {
            const int v = base + t * ST;
            P1[le] = ld4h(pin + NV + v);
            if (!trim) {
                P0[le] = ld4h(pin + v);
                P2[le] = ld4h(pin + 2 * NV + v);
                Xr[le] = ld4(x + v);
            } else { P0[le] = f4z(); P2[le] = f4z(); Xr[le] = f4z(); }
        } else {
            P0[le] = f4z(); P1[le] = f4z(); P2[le] = f4z(); Xr[le] = f4z();
        }
        O[le] = f4z();
    }
    cone_run<ELO, EHI>(Xr, P0, P1, P2, O, sh, rg, c, b, fg, w, f0, tb, s);
    #pragma unroll
    for (int le = 0; le < GR; ++le) {
        const int e = e0 + le;
        if (e >= HH && e < HH + RR) {
            const int v = base + (tb + e) * ST;
            st4h(pout + v, P0[le]);
            st4h(pout + NV + v, P1[le]);
            st4h(pout + 2 * NV + v, P2[le]);
        }
    }
}

__global__ __launch_bounds__(512, 2)
void k_mid(const float* __restrict__ x, const __half* __restrict__ pin,
           __half* __restrict__ pout, const float* __restrict__ lam) {
    __shared__ ConeShared sh;
    const int tid = threadIdx.x;
    const int blk = blockIdx.x;
    const int rg  = tid >> 8;
    const int c   = tid & 255;
    const int b   = tid & 7;
    const int fg  = (tid >> 3) & 7;
    const int w   = (tid >> 6) & 3;
    const int f0  = w * 32 + fg * 4;
    const int tb  = blk * RR - HH;
    const int e0  = rg * GR;
    const int base = b * SB + f0;
    const float s = TAU / lam[0];
    if (blk == 0 || blk == NBLK - 1)
        mid_main<true, true>(x, pin, pout, sh, rg, c, b, fg, w, f0, tb, e0, base, s);
    else
        mid_main<false, false>(x, pin, pout, sh, rg, c, b, fg, w, f0, tb, e0, base, s);
}

template<bool ELO, bool EHI>
__device__ __forceinline__ void first_main(
    const float* __restrict__ x, __half* __restrict__ pout,
    ConeShared& sh, int rg, int c, int b, int fg, int w, int f0, int tb, int e0,
    int base, float s) {
    float4 P0[GR], P1[GR], P2[GR], O[GR], Xr[GR], XHa;
    #pragma unroll
    for (int le = 0; le < GR; ++le) {
        const int t = tb + e0 + le;
        const bool ok = (!ELO || t >= 0) && (!EHI || t < TT);
        Xr[le] = ok ? ld4(x + base + t * ST) : f4z();
        O[le] = f4z();
    }
    {
        const int t = tb + e0 + GR;
        const bool ok = (!ELO || t >= 0) && (t < TT);
        XHa = ok ? ld4(x + base + t * ST) : f4z();
    }
    #pragma unroll
    for (int le = 0; le < GR; ++le) {
        const int t = tb + e0 + le;
        if ((!ELO || t >= 0) && (!EHI || t < TT)) {
            const float4 cc = Xr[le];
            const float4 nxt = (le < GR - 1) ? Xr[le + 1] : XHa;
            float4 gT = f4z();
            if (t < TT - 1) gT = sub4(nxt, cc);
            const float4 nB = dpp_dn4(cc);
            float4 gB = f4z();
            if (b < BB - 1) gB = sub4(nB, cc);
            float4 gF;
            gF.x = cc.y - cc.x;
            gF.y = cc.z - cc.y;
            gF.z = cc.w - cc.z;
            gF.w = (f0 < FF - 4) ? (x[base + t * ST + 4] - cc.w) : 0.f;
            const float4 nb = nbvec(gB, gT, gF, s);
            P0[le] = make_float4(-TAU * gB.x * nb.x, -TAU * gB.y * nb.y,
                                 -TAU * gB.z * nb.z, -TAU * gB.w * nb.w);
            P1[le] = make_float4(-TAU * gT.x * nb.x, -TAU * gT.y * nb.y,
                                 -TAU * gT.z * nb.z, -TAU * gT.w * nb.w);
            P2[le] = make_float4(-TAU * gF.x * nb.x, -TAU * gF.y * nb.y,
                                 -TAU * gF.z * nb.z, -TAU * gF.w * nb.w);
        } else {
            P0[le] = f4z(); P1[le] = f4z(); P2[le] = f4z();
        }
    }
    cone_run<ELO, EHI>(Xr, P0, P1, P2, O, sh, rg, c, b, fg, w, f0, tb, s);
    #pragma unroll
    for (int le = 0; le < GR; ++le) {
        const int e = e0 + le;
        if (e >= HH && e < HH + RR) {
            const int v = base + (tb + e) * ST;
            st4h(pout + v, P0[le]);
            st4h(pout + NV + v, P1[le]);
            st4h(pout + 2 * NV + v, P2[le]);
        }
    }
}

__global__ __launch_bounds__(512, 2)
void k_first(const float* __restrict__ x, __half* __restrict__ pout,
             const float* __restrict__ lam) {
    __shared__ ConeShared sh;
    const int tid = threadIdx.x;
    const int blk = blockIdx.x;
    const int rg  = tid >> 8;
    const int c   = tid & 255;
    const int b   = tid & 7;
    const int fg  = (tid >> 3) & 7;
    const int w   = (tid >> 6) & 3;
    const int f0  = w * 32 + fg * 4;
    const int tb  = blk * RR - HH;
    const int e0  = rg * GR;
    const int base = b * SB + f0;
    const float s = TAU / lam[0];
    if (blk == 0 || blk == NBLK - 1)
        first_main<true, true>(x, pout, sh, rg, c, b, fg, w, f0, tb, e0, base, s);
    else
        first_main<false, false>(x, pout, sh, rg, c, b, fg, w, f0, tb, e0, base, s);
}

// ==================================================================
// ============== packed-P cone tail (EE=18, GR=9) ===================
// ==================================================================
struct ConeSharedT {                     // ~10.8 KB
    float p2b[EET][4][8];
    float outx[EET][4][8];
    h4 p1if[256];
    float4 oif[256];
};

template<int RG>
__device__ __forceinline__ void publish_t(int k, h4 (&P1)[GRT], h4 (&P2)[GRT],
                                          ConeSharedT& sh, int c, int b, int fg, int w) {
    if (fg == 7) {
        #pragma unroll
        for (int le = 0; le < GRT; ++le) {
            const int e = RG * GRT + le;
            if (e >= k && e < EET - k) sh.p2b[e][w][b] = __high2float(P2[le].hi);
        }
    }
    if (RG == 0) sh.p1if[c] = P1[GRT - 1];
}

template<int RG, bool ELO, bool EHI>
__device__ __forceinline__ void phase_out_t(
    int k, const float4 (&Xr)[GRT],
    h4 (&P0)[GRT], h4 (&P1)[GRT], h4 (&P2)[GRT], float4 (&O)[GRT],
    ConeSharedT& sh, int c, int b, int fg, int w, int f0, int tb) {
    #pragma unroll
    for (int le = 0; le < GRT; ++le) {
        const int e = RG * GRT + le;
        if (e < k + 1 || e >= EET - k) continue;
        const int t = tb + e;
        if ((ELO && t < 0) || (EHI && t >= TT)) continue;
        const float4 X = Xr[le];
        const float4 p0 = h2f(P0[le]);
        const float4 p1 = h2f(P1[le]);
        const float4 p2 = h2f(P2[le]);
        float4 o;
        o.x = X.x - p0.x - p1.x - p2.x;
        o.y = X.y - p0.y - p1.y - p2.y + p2.x;
        o.z = X.z - p0.z - p1.z - p2.z + p2.y;
        o.w = X.w - p0.w - p1.w - p2.w + p2.z;
        const float4 h0 = h2f(dpp_up_h4(P0[le]));
        if (b > 0) { o.x += h0.x; o.y += h0.y; o.z += h0.z; o.w += h0.w; }
        const h4 pm1h = (le > 0) ? P1[le - 1] : sh.p1if[c];
        const float4 pm1 = h2f(pm1h);
        if (!ELO || t > 0) { o.x += pm1.x; o.y += pm1.y; o.z += pm1.z; o.w += pm1.w; }
        float pw = __shfl_up(p2.w, 8);
        if (fg == 0) pw = (w > 0) ? sh.p2b[e][(w - 1)][b] : 0.0f;
        if (f0 > 0) o.x += pw;
        O[le] = o;
        if (fg == 0) sh.outx[e][w][b] = o.x;
    }
}

template<int RG, bool ELO, bool EHI>
__device__ __forceinline__ void phase_upd_t(
    int k, h4 (&P0)[GRT], h4 (&P1)[GRT], h4 (&P2)[GRT], float4 (&O)[GRT],
    ConeSharedT& sh, int c, int b, int fg, int w, int f0, int tb, float s) {
    #pragma unroll
    for (int le = 0; le < GRT; ++le) {
        const int e = RG * GRT + le;
        if (e < k + 1 || e > EET - 2 - k) continue;
        const int t = tb + e;
        if ((ELO && t < 0) || (EHI && t >= TT)) continue;
        const float4 cc = O[le];
        const float4 on = (le < GRT - 1) ? O[le + 1] : sh.oif[c];
        float4 gT = f4z();
        if (!EHI || t < TT - 1) gT = sub4(on, cc);
        const float4 nB = dpp_dn4(cc);
        float4 gB = f4z();
        if (b < BB - 1) gB = sub4(nB, cc);
        float nxx = __shfl_down(cc.x, 8);
        if (fg == 7) nxx = (w < 3) ? sh.outx[e][w + 1][b] : 0.0f;
        float4 gF;
        gF.x = cc.y - cc.x;
        gF.y = cc.z - cc.y;
        gF.z = cc.w - cc.z;
        gF.w = (f0 < FF - 4) ? (nxx - cc.w) : 0.f;
        const float4 nb = nbvec(gB, gT, gF, s);
        const float4 p0 = h2f(P0[le]);
        const float4 p1 = h2f(P1[le]);
        const float4 p2 = h2f(P2[le]);
        float4 n0, n1, n2;
        n0.x = fmaf(-TAU, gB.x, p0.x) * nb.x;
        n0.y = fmaf(-TAU, gB.y, p0.y) * nb.y;
        n0.z = fmaf(-TAU, gB.z, p0.z) * nb.z;
        n0.w = fmaf(-TAU, gB.w, p0.w) * nb.w;
        n1.x = fmaf(-TAU, gT.x, p1.x) * nb.x;
        n1.y = fmaf(-TAU, gT.y, p1.y) * nb.y;
        n1.z = fmaf(-TAU, gT.z, p1.z) * nb.z;
        n1.w = fmaf(-TAU, gT.w, p1.w) * nb.w;
        n2.x = fmaf(-TAU, gF.x, p2.x) * nb.x;
        n2.y = fmaf(-TAU, gF.y, p2.y) * nb.y;
        n2.z = fmaf(-TAU, gF.z, p2.z) * nb.z;
        n2.w = fmaf(-TAU, gF.w, p2.w) * nb.w;
        P0[le] = f2h(n0);
        P1[le] = f2h(n1);
        P2[le] = f2h(n2);
    }
}

template<bool ELO, bool EHI>
__device__ __forceinline__ void tail_main(
    const float* __restrict__ x, const __half* __restrict__ pin,
    const float* __restrict__ bias, float* __restrict__ out,
    ConeSharedT& sh, int rg, int c, int b, int fg, int w, int f0, int tb, int e0,
    int base, float s) {
    h4 P0[GRT], P1[GRT], P2[GRT];
    float4 O[GRT], Xr[GRT];
    #pragma unroll
    for (int le = 0; le < GRT; ++le) {
        const int t = tb + e0 + le;
        const bool ok = (!ELO || t >= 0) && (!EHI || t < TT);
        const bool trim = (rg == 0 && le == 0);          // row 0: only P1 ever read
        if (ok) {
            const int v = base + t * ST;
            P1[le] = ld4hp(pin + NV + v);
            if (!trim) {
                P0[le] = ld4hp(pin + v);
                P2[le] = ld4hp(pin + 2 * NV + v);
                Xr[le] = ld4(x + v);
            } else { P0[le] = h4z(); P2[le] = h4z(); Xr[le] = f4z(); }
        } else {
            P0[le] = h4z(); P1[le] = h4z(); P2[le] = h4z(); Xr[le] = f4z();
        }
        O[le] = f4z();
    }
    // 4 cone iterations (iters 26..29)
    #pragma unroll
    for (int k = 0; k < 4; ++k) {
        if (rg == 0) publish_t<0>(k, P1, P2, sh, c, b, fg, w);
        else         publish_t<1>(k, P1, P2, sh, c, b, fg, w);
        __syncthreads();
        if (rg == 0) phase_out_t<0, ELO, EHI>(k, Xr, P0, P1, P2, O, sh, c, b, fg, w, f0, tb);
        else         phase_out_t<1, ELO, EHI>(k, Xr, P0, P1, P2, O, sh, c, b, fg, w, f0, tb);
        if (rg == 1) sh.oif[c] = O[0];
        __syncthreads();
        if (rg == 0) phase_upd_t<0, ELO, EHI>(k, P0, P1, P2, O, sh, c, b, fg, w, f0, tb, s);
        else         phase_upd_t<1, ELO, EHI>(k, P0, P1, P2, O, sh, c, b, fg, w, f0, tb, s);
    }
    // final div with 29-update p: publish(k=4) -> barrier -> phase_out(k=4)
    __syncthreads();                                     // upd writes settled (reg-only; sync for LDS reuse)
    if (rg == 0) publish_t<0>(4, P1, P2, sh, c, b, fg, w);
    else         publish_t<1>(4, P1, P2, sh, c, b, fg, w);
    __syncthreads();
    if (rg == 0) phase_out_t<0, ELO, EHI>(4, Xr, P0, P1, P2, O, sh, c, b, fg, w, f0, tb);
    else         phase_out_t<1, ELO, EHI>(4, Xr, P0, P1, P2, O, sh, c, b, fg, w, f0, tb);
    const float4 bi = ld4(bias + f0);
    #pragma unroll
    for (int le = 0; le < GRT; ++le) {
        const int e = e0 + le;
        if (e >= HLT && e < HLT + RR) {                  // owned rows rel [5,13)
            const int t = tb + e;
            const float4 o = O[le];
            st4(out + base + t * ST,
                make_float4(o.x + bi.x, o.y + bi.y, o.z + bi.z, o.w + bi.w));
        }
    }
}

__global__ __launch_bounds__(512, 2)
void k_tail(const float* __restrict__ x, const __half* __restrict__ pin,
            const float* __restrict__ lam, const float* __restrict__ bias,
            float* __restrict__ out) {
    __shared__ ConeSharedT sh;
    const int tid = threadIdx.x;
    const int blk = blockIdx.x;
    const int rg  = tid >> 8;
    const int c   = tid & 255;
    const int b   = tid & 7;
    const int fg  = (tid >> 3) & 7;
    const int w   = (tid >> 6) & 3;
    const int f0  = w * 32 + fg * 4;
    const int tb  = blk * RR - HLT;
    const int e0  = rg * GRT;
    const int base = b * SB + f0;
    const float s = TAU / lam[0];
    if (blk == 0 || blk == NBLK - 1)
        tail_main<true, true>(x, pin, bias, out, sh, rg, c, b, fg, w, f0, tb, e0, base, s);
    else
        tail_main<false, false>(x, pin, bias, out, sh, rg, c, b, fg, w, f0, tb, e0, base, s);
}

extern "C" void kernel_launch(void* const* d_in, const int* in_sizes, int n_in,
                              void* d_out, int out_size, void* d_ws, size_t ws_size,
                              hipStream_t stream) {
    const float* x    = (const float*)d_in[0];
    const float* lam  = (const float*)d_in[1];
    const float* bias = (const float*)d_in[2];
    float* out = (float*)d_out;

    __half* pA = (__half*)d_ws;                   // 3*NV halfs = 12.6 MB
    __half* pB = pA + 3 * NV;

    // iterations 1..5 (iter-1 specialization + 4 cone iters)
    k_first<<<NBLK, 512, 0, stream>>>(x, pA, lam);
    // iterations 6..25: 5 launches x 4
    __half* pin = pA;
    __half* pout = pB;
    for (int i = 0; i < 5; ++i) {
        k_mid<<<NBLK, 512, 0, stream>>>(x, pin, pout, lam);
        __half* tmp = pin; pin = pout; pout = tmp;
    }
    // iterations 26..29 + fused out = x + div(p) + bias
    k_tail<<<NBLK, 512, 0, stream>>>(x, pin, lam, bias, out);
}